// Round 1
// baseline (112.118 us; speedup 1.0000x reference)
//
#include <hip/hip_runtime.h>
#include <hip/hip_bf16.h>
#include <float.h>

// Problem constants from the reference
#define ROW 1000
#define TOP_K 10
#define NUM_EVAL_NEG 999

// One block per user. Each user has ROW=1000 (logit, dup) entries.
// position = count of elements whose masked logit is strictly greater than
// element 0's masked logit (stable argsort tie-break favors index 0).
__global__ __launch_bounds__(256) void metric_kernel(
    const float* __restrict__ logits,   // (N*ROW, 1, 2) flat
    const int*   __restrict__ dup,      // (N*ROW, 1, 1) flat
    float* __restrict__ out,            // [in_top_k(N) | ndcg(N) | weights(N)]
    int num_users)
{
    const int user = blockIdx.x;
    if (user >= num_users) return;
    const long long base = (long long)user * ROW;
    const float BIG_NEG = -FLT_MAX;  // jnp.finfo(float32).min

    // masked value of element 0 (broadcast load, L1-served for all threads)
    const int   d0 = dup[base];
    const float l0 = logits[2 * base + 1];
    const float x0 = d0 ? BIG_NEG : l0;

    const int tid = threadIdx.x;
    const float2* lg2 = reinterpret_cast<const float2*>(logits) + base;
    const int* dp = dup + base;

    int cnt = 0;   // elements strictly greater than x0
    int dsum = 0;  // sum of dup mask

    for (int j = tid; j < ROW; j += 256) {
        float2 lp = lg2[j];          // coalesced 8B/lane
        int d = dp[j];               // coalesced 4B/lane
        float m = d ? BIG_NEG : lp.y;
        cnt  += (m > x0) ? 1 : 0;
        dsum += d;
    }

    // wave-64 butterfly reduce
    #pragma unroll
    for (int off = 32; off > 0; off >>= 1) {
        cnt  += __shfl_down(cnt, off, 64);
        dsum += __shfl_down(dsum, off, 64);
    }

    __shared__ int s_cnt[4], s_dsum[4];
    const int wave = tid >> 6;
    if ((tid & 63) == 0) { s_cnt[wave] = cnt; s_dsum[wave] = dsum; }
    __syncthreads();

    if (tid == 0) {
        int c  = s_cnt[0] + s_cnt[1] + s_cnt[2] + s_cnt[3];
        int ds = s_dsum[0] + s_dsum[1] + s_dsum[2] + s_dsum[3];
        float pos  = (float)c;
        float itk  = (pos < (float)TOP_K) ? 1.0f : 0.0f;
        float ndcg = (itk != 0.0f) ? (0.69314718055994530942f / logf(pos + 2.0f)) : 0.0f;
        float w    = (ds != NUM_EVAL_NEG) ? 1.0f : 0.0f;
        out[user]                 = itk;
        out[num_users + user]     = ndcg;
        out[2 * num_users + user] = w;
    }
}

extern "C" void kernel_launch(void* const* d_in, const int* in_sizes, int n_in,
                              void* d_out, int out_size, void* d_ws, size_t ws_size,
                              hipStream_t stream) {
    const float* logits = (const float*)d_in[0];  // (N*ROW, 1, 2) fp32
    const int*   dup    = (const int*)d_in[1];    // (N*ROW, 1, 1) int32
    float* out = (float*)d_out;                   // 3*N floats

    const int num_users = in_sizes[0] / (2 * ROW);

    metric_kernel<<<num_users, 256, 0, stream>>>(logits, dup, out, num_users);
}

// Round 2
// 111.080 us; speedup vs baseline: 1.0094x; 1.0094x over previous
//
#include <hip/hip_runtime.h>
#include <hip/hip_bf16.h>
#include <float.h>

// Problem constants from the reference
#define ROW 1000
#define ROW4 (ROW / 2)   // 500 float4-of-pairs per user
#define TOP_K 10
#define NUM_EVAL_NEG 999
#define USERS_PER_BLOCK 4

// One wave (64 lanes) per user; 4 users per 256-thread block.
// position = count of elements whose masked logit is strictly greater than
// element 0's masked logit (stable argsort tie-break favors index 0).
__global__ __launch_bounds__(256) void metric_kernel(
    const float* __restrict__ logits,   // (N*ROW, 1, 2) flat
    const int*   __restrict__ dup,      // (N*ROW, 1, 1) flat
    float* __restrict__ out,            // [in_top_k(N) | ndcg(N) | weights(N)]
    int num_users)
{
    const int tid  = threadIdx.x;
    const int lane = tid & 63;
    const int user = blockIdx.x * USERS_PER_BLOCK + (tid >> 6);
    if (user >= num_users) return;

    const float BIG_NEG = -FLT_MAX;  // jnp.finfo(float32).min
    const long long base = (long long)user * ROW;   // element index

    // masked value of element 0 (one scalar-ish load per wave; L1/L2 served)
    const int   d0 = dup[base];
    const float l0 = logits[2 * base + 1];
    const float x0 = d0 ? BIG_NEG : l0;

    // 16B/lane logit loads (2 pairs), 8B/lane dup loads (2 masks)
    const float4* lg4 = reinterpret_cast<const float4*>(logits + 2 * base);
    const int2*   dp2 = reinterpret_cast<const int2*>(dup + base);

    int cnt = 0;   // elements strictly greater than x0
    int dsum = 0;  // sum of dup mask

    #pragma unroll 2
    for (int j = lane; j < ROW4; j += 64) {
        float4 lp = lg4[j];
        int2   d  = dp2[j];
        float m0 = d.x ? BIG_NEG : lp.y;
        float m1 = d.y ? BIG_NEG : lp.w;
        cnt  += (m0 > x0) ? 1 : 0;
        cnt  += (m1 > x0) ? 1 : 0;
        dsum += d.x + d.y;
    }

    // wave-64 butterfly reduce (no LDS, no syncthreads)
    #pragma unroll
    for (int off = 32; off > 0; off >>= 1) {
        cnt  += __shfl_down(cnt, off, 64);
        dsum += __shfl_down(dsum, off, 64);
    }

    if (lane == 0) {
        float pos  = (float)cnt;
        float itk  = (pos < (float)TOP_K) ? 1.0f : 0.0f;
        float ndcg = (itk != 0.0f) ? (0.69314718055994530942f / logf(pos + 2.0f)) : 0.0f;
        float w    = (dsum != NUM_EVAL_NEG) ? 1.0f : 0.0f;
        out[user]                 = itk;
        out[num_users + user]     = ndcg;
        out[2 * num_users + user] = w;
    }
}

extern "C" void kernel_launch(void* const* d_in, const int* in_sizes, int n_in,
                              void* d_out, int out_size, void* d_ws, size_t ws_size,
                              hipStream_t stream) {
    const float* logits = (const float*)d_in[0];  // (N*ROW, 1, 2) fp32
    const int*   dup    = (const int*)d_in[1];    // (N*ROW, 1, 1) int32
    float* out = (float*)d_out;                   // 3*N floats

    const int num_users = in_sizes[0] / (2 * ROW);
    const int grid = (num_users + USERS_PER_BLOCK - 1) / USERS_PER_BLOCK;

    metric_kernel<<<grid, 256, 0, stream>>>(logits, dup, out, num_users);
}

// Round 5
// 110.582 us; speedup vs baseline: 1.0139x; 1.0045x over previous
//
#include <hip/hip_runtime.h>
#include <hip/hip_bf16.h>
#include <float.h>

// Problem constants from the reference
#define ROW 1000
#define SLOTS (ROW / 4)   // 250 4-element slots per user
#define TOP_K 10
#define NUM_EVAL_NEG 999
#define USERS_PER_BLOCK 4

// NOTE: __builtin_nontemporal_load was tried (R4) and FAILED the harness's
// post-timing re-validation: nt reads can bypass L2 and observe stale HBM
// after the harness's hipMemcpyAsync input-restore. Plain loads only.
typedef float vfloat4 __attribute__((ext_vector_type(4)));
typedef int   vint4   __attribute__((ext_vector_type(4)));

// One wave (64 lanes) per user; 4 users per 256-thread block.
// position = count of elements whose masked logit is strictly greater than
// element 0's masked logit (stable argsort tie-break favors index 0).
// Since masked dup'd values are exactly BIG_NEG and x0 >= BIG_NEG, the
// predicate factorizes: count = sum_j (dup[j]==0 && logit[j] > x0).
__global__ __launch_bounds__(256) void metric_kernel(
    const float* __restrict__ logits,   // (N*ROW, 1, 2) flat
    const int*   __restrict__ dup,      // (N*ROW, 1, 1) flat
    float* __restrict__ out,            // [in_top_k(N) | ndcg(N) | weights(N)]
    int num_users)
{
    const int tid  = threadIdx.x;
    const int lane = tid & 63;
    const int user = blockIdx.x * USERS_PER_BLOCK + (tid >> 6);
    if (user >= num_users) return;

    const float BIG_NEG = -FLT_MAX;  // jnp.finfo(float32).min
    const long long base = (long long)user * ROW;   // element index

    // masked value of element 0 (one load per wave; cache-served)
    const int   d0 = dup[base];
    const float l0 = logits[2 * base + 1];
    const float x0 = d0 ? BIG_NEG : l0;

    // All loads 16B/lane: 2x float4 (4 logit pairs) + 1x int4 (4 masks).
    // base*8 bytes and base*4 bytes are both 16-aligned (ROW*4 = 4000 % 16 == 0).
    const vfloat4* lg4 = reinterpret_cast<const vfloat4*>(logits + 2 * base);
    const vint4*   dp4 = reinterpret_cast<const vint4*>(dup + base);

    int cnt = 0;   // elements strictly greater than x0
    int dsum = 0;  // sum of dup mask

    #pragma unroll 2
    for (int s = lane; s < SLOTS; s += 64) {
        vfloat4 a = lg4[2 * s];
        vfloat4 b = lg4[2 * s + 1];
        vint4   d = dp4[s];
        cnt += (d.x == 0 && a.y > x0) ? 1 : 0;
        cnt += (d.y == 0 && a.w > x0) ? 1 : 0;
        cnt += (d.z == 0 && b.y > x0) ? 1 : 0;
        cnt += (d.w == 0 && b.w > x0) ? 1 : 0;
        dsum += d.x + d.y + d.z + d.w;
    }

    // wave-64 butterfly reduce (no LDS, no syncthreads)
    #pragma unroll
    for (int off = 32; off > 0; off >>= 1) {
        cnt  += __shfl_down(cnt, off, 64);
        dsum += __shfl_down(dsum, off, 64);
    }

    if (lane == 0) {
        float pos  = (float)cnt;
        float itk  = (pos < (float)TOP_K) ? 1.0f : 0.0f;
        float ndcg = (itk != 0.0f) ? (0.69314718055994530942f / logf(pos + 2.0f)) : 0.0f;
        float w    = (dsum != NUM_EVAL_NEG) ? 1.0f : 0.0f;
        out[user]                 = itk;
        out[num_users + user]     = ndcg;
        out[2 * num_users + user] = w;
    }
}

extern "C" void kernel_launch(void* const* d_in, const int* in_sizes, int n_in,
                              void* d_out, int out_size, void* d_ws, size_t ws_size,
                              hipStream_t stream) {
    const float* logits = (const float*)d_in[0];  // (N*ROW, 1, 2) fp32
    const int*   dup    = (const int*)d_in[1];    // (N*ROW, 1, 1) int32
    float* out = (float*)d_out;                   // 3*N floats

    const int num_users = in_sizes[0] / (2 * ROW);
    const int grid = (num_users + USERS_PER_BLOCK - 1) / USERS_PER_BLOCK;

    metric_kernel<<<grid, 256, 0, stream>>>(logits, dup, out, num_users);
}